// Round 1
// baseline (40.447 us; speedup 1.0000x reference)
//
#include <hip/hip_runtime.h>

#define VOCAB 30522
#define D 768
#define NC 9
#define NROWS (32 * 512)   // 16384 rows (B*S)

// Workspace layout (bytes):
//   [0,            122088)  seg_sum  float[30522]
//   [122088,       244176)  seg_cnt  float[30522]
//   [244176,       244240)  wsum2    float[9] (+pad)
//   [244240,       834064)  partial  float[NROWS*9]
#define WS_SEG_BYTES   244176
#define WS_WSUM2_OFF   244176
#define WS_PARTIAL_OFF 244240
#define WS_FULL_NEED   834064

// ---------------------------------------------------------------------------
// Wsum2[c] = sum_{d=768..1535} W[d*9+c].  1 block of 576 threads = 9 waves,
// wave w reduces column w.
// ---------------------------------------------------------------------------
__global__ void wsum2_kernel(const float* __restrict__ W, float* __restrict__ wsum2) {
    const int lane = threadIdx.x & 63;
    const int w    = threadIdx.x >> 6;   // 0..8
    float s = 0.0f;
    #pragma unroll
    for (int k = 0; k < 12; ++k) {
        int d = 768 + lane + 64 * k;
        s += W[d * 9 + w];
    }
    #pragma unroll
    for (int off = 32; off; off >>= 1) s += __shfl_xor(s, off, 64);
    if (lane == 0) wsum2[w] = s;
}

// ---------------------------------------------------------------------------
// Row kernel: one wave per row.  Each lane loads 3 float4 (d = 4*(lane+64k)+j)
// and accumulates 9 partial dots with W (hoisted into registers) + the row sum.
// Butterfly-reduce 10 values across the wave.
//   MODE 0: atomics into seg tables + store 9 partial dots
//   MODE 1: atomics only (fallback, no partial storage)
//   MODE 2: recompute dots, read seg tables, write final output (fallback)
// ---------------------------------------------------------------------------
template <int MODE>
__global__ __launch_bounds__(256) void row_kernel(
    const float* __restrict__ h,        // [NROWS, 768]
    const float* __restrict__ W,        // [1536, 9]
    const int*   __restrict__ ids,      // [NROWS]
    float* __restrict__ seg_sum,
    float* __restrict__ seg_cnt,
    float* __restrict__ partial,        // [NROWS, 9] (MODE 0)
    const float* __restrict__ wsum2,    // [9]        (MODE 2)
    const float* __restrict__ bias,     // [9]        (MODE 2)
    float* __restrict__ out)            // [NROWS, 9] (MODE 2)
{
    const int lane = threadIdx.x & 63;
    const int wave = threadIdx.x >> 6;  // 0..3

    // Hoist this lane's W values into registers: 12 d's x 9 c's = 108 floats.
    float wreg[3][4][9];
    #pragma unroll
    for (int k = 0; k < 3; ++k) {
        #pragma unroll
        for (int j = 0; j < 4; ++j) {
            const int d = 4 * (lane + 64 * k) + j;
            #pragma unroll
            for (int c = 0; c < 9; ++c) wreg[k][j][c] = W[d * 9 + c];
        }
    }

    for (int row = blockIdx.x * 4 + wave; row < NROWS; row += gridDim.x * 4) {
        const float4* __restrict__ hrow = (const float4*)(h + (size_t)row * D);
        float acc[10];
        #pragma unroll
        for (int t = 0; t < 10; ++t) acc[t] = 0.0f;

        #pragma unroll
        for (int k = 0; k < 3; ++k) {
            float4 v = hrow[lane + 64 * k];
            float vals[4] = {v.x, v.y, v.z, v.w};
            #pragma unroll
            for (int j = 0; j < 4; ++j) {
                acc[9] += vals[j];
                #pragma unroll
                for (int c = 0; c < 9; ++c) acc[c] = fmaf(vals[j], wreg[k][j][c], acc[c]);
            }
        }

        // Butterfly reduction across the 64-lane wave (all lanes end with totals).
        #pragma unroll
        for (int off = 32; off; off >>= 1) {
            #pragma unroll
            for (int t = 0; t < 10; ++t) acc[t] += __shfl_xor(acc[t], off, 64);
        }

        if (lane == 0) {
            const int id = ids[row];
            if (MODE == 0 || MODE == 1) {
                const float mean = acc[9] * (1.0f / 768.0f);
                atomicAdd(seg_sum + id, mean);
                atomicAdd(seg_cnt + id, 1.0f);
            }
            if (MODE == 0) {
                #pragma unroll
                for (int c = 0; c < 9; ++c) partial[(size_t)row * 9 + c] = acc[c];
            }
            if (MODE == 2) {
                const float cnt = seg_cnt[id];
                const float ctx = seg_sum[id] / fmaxf(cnt, 1.0f);
                #pragma unroll
                for (int c = 0; c < 9; ++c)
                    out[(size_t)row * 9 + c] = acc[c] + ctx * wsum2[c] + bias[c];
            }
        }
    }
}

// ---------------------------------------------------------------------------
// Finalize: out[row,c] = partial[row,c] + seg_mean(ids[row]) * wsum2[c] + b[c]
// ---------------------------------------------------------------------------
__global__ __launch_bounds__(256) void finalize_kernel(
    const float* __restrict__ partial,
    const int*   __restrict__ ids,
    const float* __restrict__ seg_sum,
    const float* __restrict__ seg_cnt,
    const float* __restrict__ wsum2,
    const float* __restrict__ bias,
    float* __restrict__ out)
{
    const int t = blockIdx.x * blockDim.x + threadIdx.x;
    if (t >= NROWS * NC) return;
    const int row = t / NC;
    const int c   = t - row * NC;
    const int id  = ids[row];
    const float cnt = seg_cnt[id];
    const float ctx = seg_sum[id] / fmaxf(cnt, 1.0f);
    out[t] = partial[t] + ctx * wsum2[c] + bias[c];
}

extern "C" void kernel_launch(void* const* d_in, const int* in_sizes, int n_in,
                              void* d_out, int out_size, void* d_ws, size_t ws_size,
                              hipStream_t stream) {
    const int*   ids = (const int*)  d_in[0];   // batch [32,512] int32
    const float* h   = (const float*)d_in[1];   // last_hidden_state [32,512,768] f32
    const float* W   = (const float*)d_in[2];   // [1536, 9] f32
    const float* b   = (const float*)d_in[3];   // [9] f32
    float* out = (float*)d_out;                 // [32,512,9] f32

    char*  ws      = (char*)d_ws;
    float* seg_sum = (float*)(ws);
    float* seg_cnt = (float*)(ws + 122088);
    float* wsum2   = (float*)(ws + WS_WSUM2_OFF);
    float* partial = (float*)(ws + WS_PARTIAL_OFF);

    // Zero the segment tables every call (atomics accumulate into them).
    hipMemsetAsync(d_ws, 0, WS_SEG_BYTES, stream);

    wsum2_kernel<<<1, 576, 0, stream>>>(W, wsum2);

    if (ws_size >= (size_t)WS_FULL_NEED) {
        // Fused path: single read of h.
        row_kernel<0><<<2048, 256, 0, stream>>>(h, W, ids, seg_sum, seg_cnt,
                                                partial, nullptr, nullptr, nullptr);
        finalize_kernel<<<(NROWS * NC + 255) / 256, 256, 0, stream>>>(
            partial, ids, seg_sum, seg_cnt, wsum2, b, out);
    } else {
        // Fallback: two sweeps over h (second sweep should be L3-resident).
        row_kernel<1><<<2048, 256, 0, stream>>>(h, W, ids, seg_sum, seg_cnt,
                                                nullptr, nullptr, nullptr, nullptr);
        row_kernel<2><<<2048, 256, 0, stream>>>(h, W, ids, seg_sum, seg_cnt,
                                                nullptr, wsum2, b, out);
    }
}